// Round 6
// baseline (412.227 us; speedup 1.0000x reference)
//
#include <hip/hip_runtime.h>
#include <stdint.h>

#define DMODEL 1024
#define NHEADS 16
#define HDIM   64
#define BB     4
#define SS     2048
#define MM     (BB*SS)                      // 8192 rows
#define QKV_ELEMS ((size_t)8388608)         // B*S*DMODEL

typedef unsigned short ushort_t;
typedef __bf16    bf16x8  __attribute__((ext_vector_type(8)));
typedef _Float16  half4   __attribute__((ext_vector_type(4)));
typedef _Float16  half2_t __attribute__((ext_vector_type(2)));
typedef float     floatx4 __attribute__((ext_vector_type(4)));

__device__ inline ushort_t f32_to_bf16(float f) {
    union { float f; uint32_t u; } v; v.f = f;
    uint32_t r = v.u + 0x7FFF + ((v.u >> 16) & 1);   // RNE
    return (ushort_t)(r >> 16);
}
__device__ inline half2_t pkrtz(float a, float b) {
    return __builtin_bit_cast(half2_t, __builtin_amdgcn_cvt_pkrtz(a, b));
}
__device__ inline void glds16(const void* g, void* l) {
    __builtin_amdgcn_global_load_lds(
        (const __attribute__((address_space(1))) unsigned int*)g,
        (__attribute__((address_space(3))) unsigned int*)l, 16, 0, 0);
}

// ---------------------------------------------------------------------------
// fp32 -> bf16 converts
// ---------------------------------------------------------------------------
__global__ __launch_bounds__(256) void convert_bf16(const float* __restrict__ in,
                                                    ushort_t* __restrict__ out) {
    size_t i = ((size_t)blockIdx.x * 256 + threadIdx.x) * 8;
    float4 a = *(const float4*)&in[i];
    float4 b = *(const float4*)&in[i + 4];
    ushort_t t[8];
    t[0] = f32_to_bf16(a.x); t[1] = f32_to_bf16(a.y);
    t[2] = f32_to_bf16(a.z); t[3] = f32_to_bf16(a.w);
    t[4] = f32_to_bf16(b.x); t[5] = f32_to_bf16(b.y);
    t[6] = f32_to_bf16(b.z); t[7] = f32_to_bf16(b.w);
    *(uint4*)&out[i] = *(uint4*)t;
}

__global__ __launch_bounds__(256) void convert_a2(
    const float* __restrict__ s0, const float* __restrict__ s1,
    ushort_t* __restrict__ d0, ushort_t* __restrict__ d1) {
    const float* src = blockIdx.y ? s1 : s0;
    ushort_t*    dst = blockIdx.y ? d1 : d0;
    size_t i = ((size_t)blockIdx.x * 256 + threadIdx.x) * 8;
    float4 a = *(const float4*)&src[i];
    float4 b = *(const float4*)&src[i + 4];
    ushort_t t[8];
    t[0] = f32_to_bf16(a.x); t[1] = f32_to_bf16(a.y);
    t[2] = f32_to_bf16(a.z); t[3] = f32_to_bf16(a.w);
    t[4] = f32_to_bf16(b.x); t[5] = f32_to_bf16(b.y);
    t[6] = f32_to_bf16(b.z); t[7] = f32_to_bf16(b.w);
    *(uint4*)&dst[i] = *(uint4*)t;
}

__global__ __launch_bounds__(256) void convert_w3(
    const float* __restrict__ w0, const float* __restrict__ w1, const float* __restrict__ w2,
    ushort_t* __restrict__ o0, ushort_t* __restrict__ o1, ushort_t* __restrict__ o2) {
    const float* src = (blockIdx.y == 0) ? w0 : (blockIdx.y == 1) ? w1 : w2;
    ushort_t*    dst = (blockIdx.y == 0) ? o0 : (blockIdx.y == 1) ? o1 : o2;
    size_t i = ((size_t)blockIdx.x * 256 + threadIdx.x) * 8;
    float4 a = *(const float4*)&src[i];
    float4 b = *(const float4*)&src[i + 4];
    ushort_t t[8];
    t[0] = f32_to_bf16(a.x); t[1] = f32_to_bf16(a.y);
    t[2] = f32_to_bf16(a.z); t[3] = f32_to_bf16(a.w);
    t[4] = f32_to_bf16(b.x); t[5] = f32_to_bf16(b.y);
    t[6] = f32_to_bf16(b.z); t[7] = f32_to_bf16(b.w);
    *(uint4*)&dst[i] = *(uint4*)t;
}

// ---------------------------------------------------------------------------
// bf16 GEMM core, software-pipelined dbuf, 1 barrier/K-step.
// OUT: 0 = bf16 scatter to [B,H,S,HDIM] (Q/K)
//      1 = f16 packed store to V^T [B,H,HDIM,S]
//      2 = fp32 row-major [M,DMODEL]
// ---------------------------------------------------------------------------
template<int OUT>
__device__ __forceinline__ void gemm_core(
    ushort_t* As, ushort_t* Bs,
    const ushort_t* __restrict__ A, const ushort_t* __restrict__ W,
    const float* __restrict__ bias, void* __restrict__ O, float scale,
    int m0, int n0)
{
    const int tid  = threadIdx.x;
    const int lane = tid & 63;
    const int quad = lane >> 4;
    const int l15  = lane & 15;
    const int wid  = tid >> 6;
    const int wr   = wid >> 1, wc = wid & 1;

    floatx4 acc[4][4];
    #pragma unroll
    for (int i = 0; i < 4; i++)
        #pragma unroll
        for (int j = 0; j < 4; j++)
            acc[i][j] = (floatx4){0.f, 0.f, 0.f, 0.f};

    // prologue: stage K-tile 0 into buffer 0
    #pragma unroll
    for (int j = 0; j < 2; j++) {
        const int p = tid + j * 256, row = p >> 2, cc = p & 3;
        glds16(&A[(size_t)(m0 + row) * DMODEL + cc * 8], &As[p * 8]);
        glds16(&W[(size_t)(n0 + row) * DMODEL + cc * 8], &Bs[p * 8]);
    }

    for (int k0 = 0; k0 < DMODEL; k0 += 32) {
        const int cb  = ((k0 >> 5) & 1) * (128 * 32);
        const int nbo = (128 * 32) - cb;
        __syncthreads();                         // buf[cb] ready, other free
        const int kn = (k0 + 32) & (DMODEL - 1); // wraps on last iter (harmless)
        #pragma unroll
        for (int j = 0; j < 2; j++) {
            const int p = tid + j * 256, row = p >> 2, cc = p & 3;
            glds16(&A[(size_t)(m0 + row) * DMODEL + kn + cc * 8], &As[nbo + p * 8]);
            glds16(&W[(size_t)(n0 + row) * DMODEL + kn + cc * 8], &Bs[nbo + p * 8]);
        }
        bf16x8 af[4], bf[4];
        #pragma unroll
        for (int i = 0; i < 4; i++)
            af[i] = *(const bf16x8*)&As[cb + (wr * 64 + i * 16 + l15) * 32 + quad * 8];
        #pragma unroll
        for (int j = 0; j < 4; j++)
            bf[j] = *(const bf16x8*)&Bs[cb + (wc * 64 + j * 16 + l15) * 32 + quad * 8];
        #pragma unroll
        for (int i = 0; i < 4; i++)
            #pragma unroll
            for (int j = 0; j < 4; j++)
                acc[i][j] = __builtin_amdgcn_mfma_f32_16x16x32_bf16(af[i], bf[j], acc[i][j], 0, 0, 0);
    }

    #pragma unroll
    for (int j = 0; j < 4; j++) {
        const int n = n0 + wc * 64 + j * 16 + l15;
        const float bn = bias[n];
        if (OUT == 1) {
            const int hh = n >> 6, dh = n & 63;
            #pragma unroll
            for (int i = 0; i < 4; i++) {
                const int m = m0 + wr * 64 + i * 16 + quad * 4;
                const int b = m >> 11, s = m & 2047;
                half4 hv;
                #pragma unroll
                for (int r = 0; r < 4; r++) hv[r] = (_Float16)(acc[i][j][r] + bn);
                *(half4*)&((ushort_t*)O)[(((size_t)(b * NHEADS + hh)) * HDIM + dh) * SS + s] = hv;
            }
        } else {
            #pragma unroll
            for (int i = 0; i < 4; i++) {
                #pragma unroll
                for (int r = 0; r < 4; r++) {
                    const int m = m0 + wr * 64 + i * 16 + quad * 4 + r;
                    float v = (acc[i][j][r] + bn) * scale;
                    if (OUT == 0) {
                        const int b = m >> 11, s = m & 2047;
                        const int hh = n >> 6, dh = n & 63;
                        ((ushort_t*)O)[(((size_t)(b * NHEADS + hh)) * SS + s) * HDIM + dh] = f32_to_bf16(v);
                    } else {
                        ((float*)O)[(size_t)m * DMODEL + n] = v;
                    }
                }
            }
        }
    }
}

// fused Q+K projection: grid (16, 64); x>>3 selects segment
__global__ __launch_bounds__(256) void gemm_qk(
    const ushort_t* __restrict__ qa, const ushort_t* __restrict__ ka,
    const ushort_t* __restrict__ Wq, const ushort_t* __restrict__ Wk,
    const float* __restrict__ bq, const float* __restrict__ bk,
    ushort_t* __restrict__ Qo, ushort_t* __restrict__ Ko, float qscale)
{
    __shared__ ushort_t As[2 * 128 * 32];
    __shared__ ushort_t Bs[2 * 128 * 32];
    const int seg = blockIdx.x >> 3;
    const int n0  = (blockIdx.x & 7) * 128;
    const int m0  = blockIdx.y * 128;
    if (seg == 0)
        gemm_core<0>(As, Bs, qa, Wq, bq, (void*)Qo, qscale, m0, n0);
    else
        gemm_core<0>(As, Bs, ka, Wk, bk, (void*)Ko, 1.0f, m0, n0);
}

__global__ __launch_bounds__(256) void gemm_v(
    const ushort_t* __restrict__ A, const ushort_t* __restrict__ W,
    const float* __restrict__ bias, ushort_t* __restrict__ O)
{
    __shared__ ushort_t As[2 * 128 * 32];
    __shared__ ushort_t Bs[2 * 128 * 32];
    gemm_core<1>(As, Bs, A, W, bias, (void*)O, 1.0f, blockIdx.y * 128, blockIdx.x * 128);
}

__global__ __launch_bounds__(256) void gemm_o(
    const ushort_t* __restrict__ A, const ushort_t* __restrict__ W,
    const float* __restrict__ bias, float* __restrict__ O)
{
    __shared__ ushort_t As[2 * 128 * 32];
    __shared__ ushort_t Bs[2 * 128 * 32];
    gemm_core<2>(As, Bs, A, W, bias, (void*)O, 1.0f, blockIdx.y * 128, blockIdx.x * 128);
}

// ---------------------------------------------------------------------------
// Flash attention, transposed-score, software-pipelined (1 barrier/tile).
// V is pre-transposed in global ([bh][dh][s] f16) so BOTH K and Vt tiles
// stage via glds16 with a 16B-chunk XOR swizzle — zero VALU staging.
// grid 1024 (XCD-swizzled), block 256 = 4 waves x 32 q.
// Scores in log2 domain (0.125*log2e folded into Q projection).
// ---------------------------------------------------------------------------
__global__ __launch_bounds__(256, 4) void attn_kernel(
    const ushort_t* __restrict__ Q, const ushort_t* __restrict__ K,
    const ushort_t* __restrict__ VT, ushort_t* __restrict__ ctx)
{
    constexpr int VOFF = 2 * 4096;                 // Vt region base (ushorts)
    __shared__ ushort_t smem[4 * 4096];            // 32 KiB: Ks dbuf + Vt dbuf
    ushort_t* Tr = smem;                           // epilogue scratch (stride 72)

    const int tid  = threadIdx.x;
    const int lane = tid & 63;
    const int wid  = tid >> 6;
    const int quad = lane >> 4;
    const int l15  = lane & 15;
    const int bid  = blockIdx.x;
    const int bh   = (bid & 7) * 8 + (bid >> 7);   // same head -> same XCD
    const int b    = bh >> 4, h = bh & 15;
    const int q0   = ((bid >> 3) & 15) * 128 + wid * 32;

    const ushort_t* Qb = Q  + (size_t)bh * SS * HDIM;
    const ushort_t* Kb = K  + (size_t)bh * SS * HDIM;
    const ushort_t* Vb = VT + (size_t)bh * HDIM * SS;   // [64 d][2048 s]

    bf16x8 qf[2][2];
    #pragma unroll
    for (int qt = 0; qt < 2; qt++)
        #pragma unroll
        for (int c = 0; c < 2; c++)
            qf[qt][c] = *(const bf16x8*)&Qb[(size_t)(q0 + qt * 16 + l15) * HDIM + c * 32 + quad * 8];

    floatx4 acc[2][4];
    #pragma unroll
    for (int qt = 0; qt < 2; qt++)
        #pragma unroll
        for (int dt = 0; dt < 4; dt++)
            acc[qt][dt] = (floatx4){0.f, 0.f, 0.f, 0.f};
    float mrun[2] = {-1e30f, -1e30f};
    float lrun[2] = {0.f, 0.f};

    // ---- prologue: stage tile 0 (K rows = keys; Vt rows = dims) ----
    #pragma unroll
    for (int j = 0; j < 2; j++) {
        const int p = tid + j * 256, row = p >> 3, cc = (p & 7) ^ (row & 7);
        glds16(&Kb[(size_t)row * HDIM + cc * 8], &smem[p * 8]);
        glds16(&Vb[(size_t)row * SS + cc * 8], &smem[VOFF + p * 8]);
    }

    const half2_t one2 = {(_Float16)1.f, (_Float16)1.f};

    for (int kt = 0; kt < SS; kt += 64) {
        const int cur = ((kt >> 6) & 1);
        const int ko  = cur * 4096;
        const int kon = 4096 - ko;
        __syncthreads();   // tile(kt) staged; other buffers free

        // ---- prefetch tile kt+64 (wraps on last iter; harmless) ----
        const int ktn = (kt + 64) & (SS - 1);
        #pragma unroll
        for (int j = 0; j < 2; j++) {
            const int p = tid + j * 256, row = p >> 3, cc = (p & 7) ^ (row & 7);
            glds16(&Kb[(size_t)(ktn + row) * HDIM + cc * 8], &smem[kon + p * 8]);
            glds16(&Vb[(size_t)row * SS + ktn + cc * 8], &smem[VOFF + kon + p * 8]);
        }

        // ---- fragments for tile kt ----
        bf16x8 kf[4][2];
        #pragma unroll
        for (int nt = 0; nt < 4; nt++) {
            const int row = nt * 16 + l15;
            #pragma unroll
            for (int c = 0; c < 2; c++) {
                const int pos = (c * 4 + quad) ^ (row & 7);
                kf[nt][c] = *(const bf16x8*)&smem[ko + row * 64 + pos * 8];
            }
        }
        half4 vf[4][4];
        #pragma unroll
        for (int kb = 0; kb < 4; kb++) {
            #pragma unroll
            for (int dt = 0; dt < 4; dt++) {
                const int row = dt * 16 + l15;            // d index
                const int u   = kb * 4 + quad;            // 8B key-unit
                const int g   = (u >> 1) ^ (row & 7);     // LDS 16B chunk
                vf[kb][dt] = *(const half4*)&smem[VOFF + ko + row * 64 + g * 8 + (u & 1) * 4];
            }
        }

        #pragma unroll
        for (int qt = 0; qt < 2; qt++) {
            floatx4 s[4];
            #pragma unroll
            for (int nt = 0; nt < 4; nt++) {
                floatx4 cz = (floatx4){0.f, 0.f, 0.f, 0.f};
                cz = __builtin_amdgcn_mfma_f32_16x16x32_bf16(kf[nt][0], qf[qt][0], cz, 0, 0, 0);
                cz = __builtin_amdgcn_mfma_f32_16x16x32_bf16(kf[nt][1], qf[qt][1], cz, 0, 0, 0);
                s[nt] = cz;
            }
            float mx = s[0][0];
            #pragma unroll
            for (int nt = 0; nt < 4; nt++)
                #pragma unroll
                for (int r = 0; r < 4; r++) mx = fmaxf(mx, s[nt][r]);
            mx = fmaxf(mx, __shfl_xor(mx, 16));
            mx = fmaxf(mx, __shfl_xor(mx, 32));
            const float mnew  = fmaxf(mrun[qt], mx);
            const float alpha = __builtin_amdgcn_exp2f(mrun[qt] - mnew);
            mrun[qt] = mnew;

            float ps = 0.f;
            half4 pf[4];
            #pragma unroll
            for (int nt = 0; nt < 4; nt++) {
                const float p0 = __builtin_amdgcn_exp2f(s[nt][0] - mnew);
                const float p1 = __builtin_amdgcn_exp2f(s[nt][1] - mnew);
                const float p2 = __builtin_amdgcn_exp2f(s[nt][2] - mnew);
                const float p3 = __builtin_amdgcn_exp2f(s[nt][3] - mnew);
                const half2_t ha = pkrtz(p0, p1);
                const half2_t hb = pkrtz(p2, p3);
                ps = __builtin_amdgcn_fdot2(ha, one2, ps, false);
                ps = __builtin_amdgcn_fdot2(hb, one2, ps, false);
                union { half4 h4; half2_t h2[2]; } u;
                u.h2[0] = ha; u.h2[1] = hb;
                pf[nt] = u.h4;
            }
            ps += __shfl_xor(ps, 16);
            ps += __shfl_xor(ps, 32);
            lrun[qt] = lrun[qt] * alpha + ps;

            #pragma unroll
            for (int dt = 0; dt < 4; dt++) acc[qt][dt] *= alpha;
            #pragma unroll
            for (int kb = 0; kb < 4; kb++)
                #pragma unroll
                for (int dt = 0; dt < 4; dt++)
                    acc[qt][dt] = __builtin_amdgcn_mfma_f32_16x16x16f16(vf[kb][dt], pf[kb], acc[qt][dt], 0, 0, 0);
        }
    }

    // ---- epilogue: per-wave LDS transpose, coalesced bf16 store ----
    __syncthreads();
    constexpr int LDT = 72;
    const float inv0 = 1.f / lrun[0], inv1 = 1.f / lrun[1];
    ushort_t* Tw = Tr + wid * (32 * LDT);
    #pragma unroll
    for (int qt = 0; qt < 2; qt++) {
        const float inv = qt ? inv1 : inv0;
        #pragma unroll
        for (int dt = 0; dt < 4; dt++)
            #pragma unroll
            for (int r = 0; r < 4; r++)
                Tw[(qt * 16 + l15) * LDT + dt * 16 + quad * 4 + r] = f32_to_bf16(acc[qt][dt][r] * inv);
    }
    __syncthreads();
    const int row = lane >> 1, hf = lane & 1;
    const ushort_t* src = Tw + row * LDT + hf * 32;
    ushort_t* dst = ctx + ((size_t)(b * SS) + q0 + row) * DMODEL + h * HDIM + hf * 32;
    #pragma unroll
    for (int i = 0; i < 4; i++)
        *(uint4*)(dst + i * 8) = *(const uint4*)(src + i * 8);
}

extern "C" void kernel_launch(void* const* d_in, const int* in_sizes, int n_in,
                              void* d_out, int out_size, void* d_ws, size_t ws_size,
                              hipStream_t stream) {
    (void)in_sizes; (void)n_in; (void)out_size; (void)ws_size;
    const float* query = (const float*)d_in[0];
    const float* key_  = (const float*)d_in[1];
    const float* value = (const float*)d_in[2];
    const float* Wq = (const float*)d_in[3];
    const float* bq = (const float*)d_in[4];
    const float* Wk = (const float*)d_in[5];
    const float* bk = (const float*)d_in[6];
    const float* Wv = (const float*)d_in[7];
    const float* bv = (const float*)d_in[8];
    const float* Wo = (const float*)d_in[9];
    const float* bo = (const float*)d_in[10];
    float* out = (float*)d_out;

    // 64 MiB workspace = 4 x 16.78 MB regions
    ushort_t* t1 = (ushort_t*)d_ws;          // qa -> va -> ctx
    ushort_t* t2 = t1 + QKV_ELEMS;           // ka -> V^T (f16 [bh][dh][s])
    ushort_t* t3 = t2 + QKV_ELEMS;           // Qw (log2-scaled) -> Wo bf16
    ushort_t* t4 = t3 + QKV_ELEMS;           // Kw
    // weight scratch parked in d_out (dead before final GEMM writes it)
    ushort_t* Wqb = (ushort_t*)d_out;
    ushort_t* Wkb = Wqb + 1048576;
    ushort_t* Wvb = Wkb + 1048576;

    dim3 blk(256);

    hipLaunchKernelGGL(convert_w3, dim3(512, 3), blk, 0, stream, Wq, Wk, Wv, Wqb, Wkb, Wvb);
    hipLaunchKernelGGL(convert_a2, dim3(4096, 2), blk, 0, stream, query, key_, t1, t2);

    // Q scale = (1/sqrt(64)) * log2(e)
    hipLaunchKernelGGL(gemm_qk, dim3(16, 64), blk, 0, stream,
                       t1, t2, Wqb, Wkb, bq, bk, t3, t4, 0.18033688011f);

    hipLaunchKernelGGL(convert_bf16, dim3(4096), blk, 0, stream, value, t1);
    hipLaunchKernelGGL(gemm_v, dim3(8, 64), blk, 0, stream, t1, Wvb, bv, t2);

    hipLaunchKernelGGL(attn_kernel, dim3(1024), blk, 0, stream, t3, t4, t2, t1);

    hipLaunchKernelGGL(convert_bf16, dim3(512), blk, 0, stream, Wo, t3);
    hipLaunchKernelGGL(gemm_o, dim3(8, 64), blk, 0, stream, t1, t3, bo, out);
}